// Round 8
// baseline (1689.582 us; speedup 1.0000x reference)
//
#include <hip/hip_runtime.h>

// ---------------------------------------------------------------------------
// S2S RNN (encoder/decoder Elman + output log-softmax) on MI355X.
// fp32 in/out, bf16 operands + fp32 accumulate internally.
//
// Round-14 == Round-13 resubmit (previous bench died to an infra failure:
// "MI355X container failed twice"; no kernel verdict). Audit found no hang
// path: scan kernel byte-identical to passing r12; out_gemm_lsm has no
// inter-WG waits and a deadlock-free barrier structure.
//
// Round-13: non-scan overhead attack. r12 post-mortem: scan = 1337 us =
// 2.61 us/step == r5's 2.59 — all handshake micro-shaves were null; the scan
// chain {store->IC ack->flag->poll->load->barrier} + 64-producer skew is the
// per-step cost and stays UNTOUCHED this round (byte-identical rnn_scan8).
// The 287 us of non-scan time has a clean 2x: the old 64x64-tile final GEMM
// re-read every A-tile 8x (~512MB) and a separate logsoftmax kernel moved
// another 201MB. Replaced by out_gemm_lsm_kernel:
//   - 512 WGs x 64 rows; bn-loop INSIDE the WG: A staged once per K-chunk
//     (A read exactly once = 64MB), B (1MB) stays L2-hot across reuse.
//   - acc[8][4] floatx4 fully #pragma-unrolled (static indexing, rule #20).
//   - log-softmax fused in the epilogue: each lane holds 4 full rows x 32
//     cols; reduce = in-register + 4 shfl_xor over the 16-lane row group;
//     writes final fp32 d_out directly with nontemporal stores. The 8192-WG
//     logsoftmax kernel and its 134MB of re-traffic are deleted.
// Kept: proj-table xp, mode-0 gemm_bt for proj, NT states stream. ws ~75 MB.
// ---------------------------------------------------------------------------

typedef short short8 __attribute__((ext_vector_type(8)));
typedef float floatx4 __attribute__((ext_vector_type(4)));
typedef unsigned int uint4v __attribute__((ext_vector_type(4)));

// ---- ws layout (~75 MB) ----
#define WS_HBUF   0ull                        // 512 KB: [2][128][1024] bf16 ping-pong
#define WS_STATES (2ull << 20)                // 64 MB: [256][128][1024] bf16
#define WS_WB     (66ull << 20)               // weights/proj/flags region

#define HS_STRIDE 1032  // shorts per LDS row (16B-aligned, +16B pad)

__device__ __forceinline__ float bf2f(unsigned short u) {
  union { unsigned u; float f; } x; x.u = ((unsigned)u) << 16; return x.f;
}
__device__ __forceinline__ unsigned short f2bf(float f) {
  union { float f; unsigned u; } x; x.f = f;
  unsigned r = x.u + 0x7FFFu + ((x.u >> 16) & 1u);  // RNE
  return (unsigned short)(r >> 16);
}

// fp32 -> bf16 bulk convert, 4 elems/thread. n multiple of 1024.
__global__ __launch_bounds__(256) void cvt_kernel(
    const float* __restrict__ src, unsigned short* __restrict__ dst, int n)
{
  const int i = (blockIdx.x * 256 + threadIdx.x) * 4;
  if (i >= n) return;
  const float4 v = *(const float4*)(src + i);
  unsigned short o[4] = {f2bf(v.x), f2bf(v.y), f2bf(v.z), f2bf(v.w)};
  *(uint2*)(dst + i) = *(const uint2*)o;
}

// ---------------------------------------------------------------------------
// C[M,N] = A[M,K] . B[N,K]^T (+ fp32 bias), bf16 operands, fp32 acc.
// 64x64 WG tile, 4 waves, wave tile 16x64 via 16x16x32 bf16 MFMA.
// (proj-table builds only; final GEMM is out_gemm_lsm_kernel below)
// ---------------------------------------------------------------------------
__global__ __launch_bounds__(256) void gemm_bt_kernel(
    const unsigned short* __restrict__ Abase,
    const int mode,
    const unsigned short* __restrict__ Bmat,
    const float* __restrict__ bias0,
    const float* __restrict__ bias1,
    unsigned short* __restrict__ outp_bf,
    float* __restrict__ outp_f,
    const int K, const int N, const int nbn)
{
  __shared__ unsigned short As[64][264];
  __shared__ unsigned short Bs[64][264];
  __shared__ const unsigned short* rowsrc[64];

  const int tid = threadIdx.x;
  const int lane = tid & 63;
  const int wave = tid >> 6;
  const int bn = blockIdx.x % nbn;
  const int bm = blockIdx.x / nbn;
  const int m0 = bm * 64;
  const int j0 = bn * 64;

  if (tid < 64) {
    const int m = m0 + tid;
    const unsigned short* src;
    if (mode == 0) {
      src = Abase + (size_t)m * K;
    } else {  // mode 3
      src = Abase + ((size_t)(m & 255) * 128 + (m >> 8)) * 1024;
    }
    rowsrc[tid] = src;
  }

  const floatx4 zf = {0.f, 0.f, 0.f, 0.f};
  floatx4 acc0 = zf, acc1 = zf, acc2 = zf, acc3 = zf;

  for (int kc = 0; kc < K; kc += 256) {
    __syncthreads();
#pragma unroll
    for (int i = 0; i < 8; ++i) {
      const int idx = i * 256 + tid;
      const int r = idx >> 5;
      const int c = idx & 31;
      const unsigned short* s = rowsrc[r];
      *(short8*)&As[r][c * 8] = *(const short8*)(s + kc + c * 8);
      *(short8*)&Bs[r][c * 8] =
          *(const short8*)(Bmat + (size_t)(j0 + r) * K + kc + c * 8);
    }
    __syncthreads();
    const int ar = 16 * wave + (lane & 15);
    const int kq = (lane >> 4) * 8;
#pragma unroll
    for (int kk = 0; kk < 8; ++kk) {
      const short8 a = *(const short8*)&As[ar][kk * 32 + kq];
      const short8 bv0 = *(const short8*)&Bs[(lane & 15)][kk * 32 + kq];
      acc0 = __builtin_amdgcn_mfma_f32_16x16x32_bf16(a, bv0, acc0, 0, 0, 0);
      const short8 bv1 = *(const short8*)&Bs[16 + (lane & 15)][kk * 32 + kq];
      acc1 = __builtin_amdgcn_mfma_f32_16x16x32_bf16(a, bv1, acc1, 0, 0, 0);
      const short8 bv2 = *(const short8*)&Bs[32 + (lane & 15)][kk * 32 + kq];
      acc2 = __builtin_amdgcn_mfma_f32_16x16x32_bf16(a, bv2, acc2, 0, 0, 0);
      const short8 bv3 = *(const short8*)&Bs[48 + (lane & 15)][kk * 32 + kq];
      acc3 = __builtin_amdgcn_mfma_f32_16x16x32_bf16(a, bv3, acc3, 0, 0, 0);
    }
  }

  float bs[4] = {0.f, 0.f, 0.f, 0.f};
  if (bias0) {
#pragma unroll
    for (int nt = 0; nt < 4; ++nt) {
      const int jj = j0 + nt * 16 + (lane & 15);
      bs[nt] = bias0[jj] + bias1[jj];
    }
  }
  __syncthreads();
  const int rbase = 16 * wave + (lane >> 4) * 4;
  const int cl = lane & 15;

  if (outp_bf) {
#pragma unroll
    for (int i = 0; i < 4; ++i) {
      As[rbase + i][cl]      = f2bf(acc0[i] + bs[0]);
      As[rbase + i][16 + cl] = f2bf(acc1[i] + bs[1]);
      As[rbase + i][32 + cl] = f2bf(acc2[i] + bs[2]);
      As[rbase + i][48 + cl] = f2bf(acc3[i] + bs[3]);
    }
    __syncthreads();
#pragma unroll
    for (int i = 0; i < 2; ++i) {
      const int idx = i * 256 + tid;
      const int r = idx >> 3;
      const int c = idx & 7;
      *(short8*)(outp_bf + (size_t)(m0 + r) * N + j0 + c * 8) =
          *(const short8*)&As[r][c * 8];
    }
  } else {
    float (*Asf)[66] = (float(*)[66]) & As[0][0];
#pragma unroll
    for (int i = 0; i < 4; ++i) {
      Asf[rbase + i][cl]      = acc0[i] + bs[0];
      Asf[rbase + i][16 + cl] = acc1[i] + bs[1];
      Asf[rbase + i][32 + cl] = acc2[i] + bs[2];
      Asf[rbase + i][48 + cl] = acc3[i] + bs[3];
    }
    __syncthreads();
#pragma unroll
    for (int i = 0; i < 4; ++i) {
      const int idx = i * 256 + tid;
      const int r = idx >> 4;
      const int c = idx & 15;
      *(float4*)(outp_f + (size_t)(m0 + r) * N + j0 + c * 4) =
          *(const float4*)&Asf[r][c * 4];
    }
  }
}

// ---------------------------------------------------------------------------
// Fused output: logits = gather(states)[M,1024] . outW[512,1024]^T + outB,
// then rowwise log_softmax, written fp32 to d_out. 512 WGs x 64 rows; the
// bn-loop is INSIDE the WG so A is staged/read once per K-chunk and each
// lane ends holding 4 complete rows x 32 cols for the in-register softmax.
// ---------------------------------------------------------------------------
__global__ __launch_bounds__(256) void out_gemm_lsm_kernel(
    const unsigned short* __restrict__ states,  // [256][128][1024]
    const unsigned short* __restrict__ Bmat,    // outW bf16 [512][1024]
    const float* __restrict__ outb,             // [512]
    float* __restrict__ outp)                   // [32768][512] fp32
{
  __shared__ unsigned short As[64][264];
  __shared__ unsigned short Bs[64][264];
  __shared__ const unsigned short* rowsrc[64];
  __shared__ float obias[512];

  const int tid = threadIdx.x;
  const int lane = tid & 63;
  const int wave = tid >> 6;
  const int m0 = blockIdx.x * 64;

  if (tid < 64) {
    const int m = m0 + tid;
    rowsrc[tid] = states + ((size_t)(m & 255) * 128 + (m >> 8)) * 1024;
  }
  obias[tid] = outb[tid];
  obias[256 + tid] = outb[256 + tid];

  const floatx4 zf = {0.f, 0.f, 0.f, 0.f};
  floatx4 acc[8][4];
#pragma unroll
  for (int bn = 0; bn < 8; ++bn)
#pragma unroll
    for (int nt = 0; nt < 4; ++nt) acc[bn][nt] = zf;

  const int ar = 16 * wave + (lane & 15);
  const int kq = (lane >> 4) * 8;

  for (int kc = 0; kc < 1024; kc += 256) {
    __syncthreads();  // prev chunk's As/Bs reads done
#pragma unroll
    for (int i = 0; i < 8; ++i) {
      const int idx = i * 256 + tid;
      const int r = idx >> 5;
      const int c = idx & 31;
      *(short8*)&As[r][c * 8] = *(const short8*)(rowsrc[r] + kc + c * 8);
    }
#pragma unroll
    for (int bn = 0; bn < 8; ++bn) {
      __syncthreads();  // As ready (bn==0) / prev bn's Bs reads done
#pragma unroll
      for (int i = 0; i < 8; ++i) {
        const int idx = i * 256 + tid;
        const int r = idx >> 5;
        const int c = idx & 31;
        *(short8*)&Bs[r][c * 8] =
            *(const short8*)(Bmat + (size_t)(bn * 64 + r) * 1024 + kc + c * 8);
      }
      __syncthreads();
#pragma unroll
      for (int kk = 0; kk < 8; ++kk) {
        const short8 a = *(const short8*)&As[ar][kk * 32 + kq];
        const short8 bv0 = *(const short8*)&Bs[(lane & 15)][kk * 32 + kq];
        acc[bn][0] = __builtin_amdgcn_mfma_f32_16x16x32_bf16(a, bv0, acc[bn][0], 0, 0, 0);
        const short8 bv1 = *(const short8*)&Bs[16 + (lane & 15)][kk * 32 + kq];
        acc[bn][1] = __builtin_amdgcn_mfma_f32_16x16x32_bf16(a, bv1, acc[bn][1], 0, 0, 0);
        const short8 bv2 = *(const short8*)&Bs[32 + (lane & 15)][kk * 32 + kq];
        acc[bn][2] = __builtin_amdgcn_mfma_f32_16x16x32_bf16(a, bv2, acc[bn][2], 0, 0, 0);
        const short8 bv3 = *(const short8*)&Bs[48 + (lane & 15)][kk * 32 + kq];
        acc[bn][3] = __builtin_amdgcn_mfma_f32_16x16x32_bf16(a, bv3, acc[bn][3], 0, 0, 0);
      }
    }
  }

  // Epilogue: bias + rowwise log-softmax fully in registers.
  // Lane holds rows rbase..rbase+3 (i), cols bn*64 + nt*16 + cl (all 512 of
  // each row across this lane's 32 values + the 15 lanes sharing lane>>4).
  const int rbase = 16 * wave + (lane >> 4) * 4;
  const int cl = lane & 15;
#pragma unroll
  for (int bn = 0; bn < 8; ++bn)
#pragma unroll
    for (int nt = 0; nt < 4; ++nt) {
      const float bv = obias[bn * 64 + nt * 16 + cl];
#pragma unroll
      for (int i = 0; i < 4; ++i) acc[bn][nt][i] += bv;
    }
  float mx[4] = {-1e30f, -1e30f, -1e30f, -1e30f};
#pragma unroll
  for (int bn = 0; bn < 8; ++bn)
#pragma unroll
    for (int nt = 0; nt < 4; ++nt)
#pragma unroll
      for (int i = 0; i < 4; ++i) mx[i] = fmaxf(mx[i], acc[bn][nt][i]);
#pragma unroll
  for (int m = 1; m < 16; m <<= 1)
#pragma unroll
    for (int i = 0; i < 4; ++i) mx[i] = fmaxf(mx[i], __shfl_xor(mx[i], m, 64));
  float sm[4] = {0.f, 0.f, 0.f, 0.f};
#pragma unroll
  for (int bn = 0; bn < 8; ++bn)
#pragma unroll
    for (int nt = 0; nt < 4; ++nt)
#pragma unroll
      for (int i = 0; i < 4; ++i) sm[i] += __expf(acc[bn][nt][i] - mx[i]);
#pragma unroll
  for (int m = 1; m < 16; m <<= 1)
#pragma unroll
    for (int i = 0; i < 4; ++i) sm[i] += __shfl_xor(sm[i], m, 64);
  float lse[4];
#pragma unroll
  for (int i = 0; i < 4; ++i) lse[i] = mx[i] + __logf(sm[i]);

#pragma unroll
  for (int bn = 0; bn < 8; ++bn)
#pragma unroll
    for (int nt = 0; nt < 4; ++nt)
#pragma unroll
      for (int i = 0; i < 4; ++i) {
        __builtin_nontemporal_store(
            acc[bn][nt][i] - lse[i],
            outp + (size_t)(m0 + rbase + i) * 512 + bn * 64 + nt * 16 + cl);
      }
}

// ---------------------------------------------------------------------------
// Round-12 recurrence (PROVEN, byte-identical). 128 WGs x 256 thr; group
// g = blockIdx&7 owns batch rows [16g,16g+16); 16 WGs/group cover 1024 cols.
// ---------------------------------------------------------------------------
__global__ __launch_bounds__(256) void rnn_scan8_kernel(
    const unsigned short* __restrict__ WhhE,
    const unsigned short* __restrict__ WhhD,
    const unsigned short* __restrict__ projE,
    const unsigned short* __restrict__ projD,
    const float* __restrict__ decBih,
    const float* __restrict__ decBhh,
    const int* __restrict__ intoks,     // inputs  [128][256] int32
    const int* __restrict__ outtoks,    // outputs [128][256] int32
    unsigned short* __restrict__ hbuf,  // [2][128][1024] ping-pong h
    unsigned short* __restrict__ states,// [256][128][1024] decoder states
    unsigned int* __restrict__ flags)   // [8][64*16] per-wave flags, 64B pad
{
  __shared__ unsigned short hs[2 * 16 * HS_STRIDE];  // double-buffered
  __shared__ int toks[16 * 257];

  const int tid = threadIdx.x;
  const int lane = tid & 63;
  const int wave = tid >> 6;                   // 0..3
  const int g = blockIdx.x & 7;
  const int slot = blockIdx.x >> 3;            // 0..15
  const int b0 = g * 16;
  const int q = lane >> 4;
  const int cl = lane & 15;
  const int jwb = slot * 64 + wave * 16;       // wave's 16-column base
  const int jq4 = jwb + q * 4;                 // this thread's 4 output columns
  unsigned int* grpflags = flags + (size_t)g * 1024;  // 64 flags x 16-u32 pad
  const int myflag = (slot * 4 + wave) * 16;

  short8 w[32];  // Whh[jwb+cl][0:1024] A-fragments — 128 VGPRs
  const floatx4 zf = {0.f, 0.f, 0.f, 0.f};
  const size_t prodoff = (size_t)(b0 + cl) * 1024 + jq4;

  for (int phase = 0; phase < 2; ++phase) {
    const unsigned short* Whh = phase ? WhhD : WhhE;
    const unsigned short* proj = phase ? projD : projE;
    const int* gt = phase ? outtoks : intoks;
    {
      const unsigned short* wp = Whh + (size_t)(jwb + cl) * 1024 + q * 8;
#pragma unroll
      for (int kk = 0; kk < 32; ++kk) w[kk] = *(const short8*)(wp + kk * 32);
    }
    float xb[4] = {0.f, 0.f, 0.f, 0.f};
    if (phase) {  // decoder t==0 input is zero -> xp = bih+bhh (fp32, exact)
#pragma unroll
      for (int i = 0; i < 4; ++i) xb[i] = decBih[jq4 + i] + decBhh[jq4 + i];
    }
    // stage this phase's token ids (16 rows x 256 steps) into LDS
    __syncthreads();
#pragma unroll
    for (int i = 0; i < 16; ++i) {
      const int idx = i * 256 + tid;
      toks[(idx >> 8) * 257 + (idx & 255)] =
          gt[(size_t)(b0 + (idx >> 8)) * 256 + (idx & 255)];
    }
    __syncthreads();

    for (int t = 0; t < 256; ++t) {
      const int s = phase * 256 + t;
      // xp gather (issued early; latency hides under the flag poll)
      float xpf[4];
      {
        const int tt = phase ? (t > 0 ? t - 1 : 0) : t;
        const int tok = toks[cl * 257 + tt];
        const uint2 xr = *(const uint2*)(proj + (size_t)tok * 1024 + jq4);
        const unsigned short* xs = (const unsigned short*)&xr;
#pragma unroll
        for (int i = 0; i < 4; ++i) xpf[i] = bf2f(xs[i]);
        if (phase && t == 0) {
#pragma unroll
          for (int i = 0; i < 4; ++i) xpf[i] = xb[i];
        }
      }

      unsigned short* hsb = hs + (s & 1) * (16 * HS_STRIDE);
      if (s > 0) {
        // EVERY wave polls all 64 per-wave flags: lane l <-> flag l.
        // flag >= s  =>  peers stored h_s AND consumed h_{s-1}.
        const unsigned target = (unsigned)s;
        for (;;) {
          const unsigned f = __hip_atomic_load(&grpflags[lane * 16],
                                               __ATOMIC_RELAXED,
                                               __HIP_MEMORY_SCOPE_AGENT);
          if (__ballot(f < target) == 0ull) break;
          __builtin_amdgcn_s_sleep(1);
        }
        // guaranteed-valid image load: 8x 16B coherent loads, one wait.
        const unsigned short* hrb = hbuf + (size_t)(s & 1) * 131072 + b0 * 1024;
        uint4v p0, p1, p2, p3, p4, p5, p6, p7;
        {
          const unsigned long long a0 = (unsigned long long)(hrb + tid * 8);
          asm volatile(
              "global_load_dwordx4 %0, %8, off sc0 sc1\n\t"
              "global_load_dwordx4 %1, %9, off sc0 sc1\n\t"
              "global_load_dwordx4 %2, %10, off sc0 sc1\n\t"
              "global_load_dwordx4 %3, %11, off sc0 sc1\n\t"
              "global_load_dwordx4 %4, %12, off sc0 sc1\n\t"
              "global_load_dwordx4 %5, %13, off sc0 sc1\n\t"
              "global_load_dwordx4 %6, %14, off sc0 sc1\n\t"
              "global_load_dwordx4 %7, %15, off sc0 sc1\n\t"
              "s_waitcnt vmcnt(0)"
              : "=&v"(p0), "=&v"(p1), "=&v"(p2), "=&v"(p3),
                "=&v"(p4), "=&v"(p5), "=&v"(p6), "=&v"(p7)
              : "v"(a0),            "v"(a0 + 1 * 4096),
                "v"(a0 + 2 * 4096), "v"(a0 + 3 * 4096),
                "v"(a0 + 4 * 4096), "v"(a0 + 5 * 4096),
                "v"(a0 + 6 * 4096), "v"(a0 + 7 * 4096)
              : "memory");
        }
        __builtin_amdgcn_sched_barrier(0);
        // stage to LDS (r5 map: chunk gg = c*256+tid -> row gg>>7, col gg&127)
        {
          uint4v pp[8] = {p0, p1, p2, p3, p4, p5, p6, p7};
#pragma unroll
          for (int c = 0; c < 8; ++c) {
            const int gg = c * 256 + tid;
            *(uint4v*)&hsb[(gg >> 7) * HS_STRIDE + (gg & 127) * 8] = pp[c];
          }
        }
      }
      // Raw barrier: drain LDS writes only; stores stay in flight.
      __builtin_amdgcn_sched_barrier(0);
      asm volatile("s_waitcnt lgkmcnt(0)" ::: "memory");
      __builtin_amdgcn_s_barrier();
      __builtin_amdgcn_sched_barrier(0);
      __builtin_amdgcn_s_setprio(1);

      floatx4 acc0 = zf, acc1 = zf, acc2 = zf, acc3 = zf;
      if (s > 0) {
        // swapped operands: thread owns (row b0+cl, cols jq4..+3)
        const unsigned short* hrow = &hsb[cl * HS_STRIDE + q * 8];
#pragma unroll
        for (int kk = 0; kk < 32; kk += 4) {
          const short8 a0 = *(const short8*)(hrow + (kk + 0) * 32);
          const short8 a1 = *(const short8*)(hrow + (kk + 1) * 32);
          const short8 a2 = *(const short8*)(hrow + (kk + 2) * 32);
          const short8 a3 = *(const short8*)(hrow + (kk + 3) * 32);
          acc0 = __builtin_amdgcn_mfma_f32_16x16x32_bf16(w[kk + 0], a0, acc0, 0, 0, 0);
          acc1 = __builtin_amdgcn_mfma_f32_16x16x32_bf16(w[kk + 1], a1, acc1, 0, 0, 0);
          acc2 = __builtin_amdgcn_mfma_f32_16x16x32_bf16(w[kk + 2], a2, acc2, 0, 0, 0);
          acc3 = __builtin_amdgcn_mfma_f32_16x16x32_bf16(w[kk + 3], a3, acc3, 0, 0, 0);
        }
      }
      unsigned short ob[4];
#pragma unroll
      for (int i = 0; i < 4; ++i) {
        const float pre = acc0[i] + acc1[i] + acc2[i] + acc3[i] + xpf[i];
        const float e = __expf(2.f * pre);
        ob[i] = f2bf(1.f - 2.f / (e + 1.f));  // tanh
      }
      const unsigned long long obp = *(const unsigned long long*)ob;
      // h store (critical handshake) -> own-wave drain -> per-wave flag.
      __hip_atomic_store(
          (unsigned long long*)(hbuf + (size_t)((s + 1) & 1) * 131072 + prodoff),
          obp, __ATOMIC_RELAXED, __HIP_MEMORY_SCOPE_AGENT);
      asm volatile("s_waitcnt vmcnt(0)" ::: "memory");
      if (lane == 0)
        __hip_atomic_store(&grpflags[myflag], (unsigned)(s + 1),
                           __ATOMIC_RELAXED, __HIP_MEMORY_SCOPE_AGENT);
      __builtin_amdgcn_s_setprio(0);
      // decoder states stream: nontemporal, AFTER publish (ack off the path).
      if (phase) {
        __builtin_nontemporal_store(
            obp, (unsigned long long*)(states + (size_t)t * 131072 + prodoff));
      }
    }
  }
}

extern "C" void kernel_launch(void* const* d_in, const int* in_sizes, int n_in,
                              void* d_out, int out_size, void* d_ws, size_t ws_size,
                              hipStream_t stream)
{
  const int* inputs  = (const int*)d_in[0];
  const int* outputs = (const int*)d_in[1];
  const float* emb    = (const float*)d_in[2];
  const float* encWih = (const float*)d_in[3];
  const float* encWhh = (const float*)d_in[4];
  const float* encBih = (const float*)d_in[5];
  const float* encBhh = (const float*)d_in[6];
  const float* decWih = (const float*)d_in[7];
  const float* decWhh = (const float*)d_in[8];
  const float* decBih = (const float*)d_in[9];
  const float* decBhh = (const float*)d_in[10];
  const float* outW   = (const float*)d_in[11];
  const float* outB   = (const float*)d_in[12];

  char* ws = (char*)d_ws;
  unsigned short* hbuf   = (unsigned short*)(ws + WS_HBUF);
  unsigned short* states = (unsigned short*)(ws + WS_STATES);
  char* wb = ws + WS_WB;
  unsigned short* embB  = (unsigned short*)(wb + 0);
  unsigned short* eWihB = (unsigned short*)(wb + (512ull << 10));
  unsigned short* dWihB = (unsigned short*)(wb + (1ull << 20));
  unsigned short* eWhhB = (unsigned short*)(wb + (2ull << 20));
  unsigned short* dWhhB = (unsigned short*)(wb + (4ull << 20));
  unsigned short* outWB = (unsigned short*)(wb + (6ull << 20));
  unsigned short* projE = (unsigned short*)(wb + (7ull << 20));
  unsigned short* projD = (unsigned short*)(wb + (8ull << 20));
  unsigned int*   flags = (unsigned int*)  (wb + (9ull << 20));
  float* logits = (float*)d_out;

  hipMemsetAsync(flags, 0, 8 * 1024 * sizeof(unsigned int), stream);

  cvt_kernel<<<128, 256, 0, stream>>>(emb, embB, 512 * 256);
  cvt_kernel<<<256, 256, 0, stream>>>(encWih, eWihB, 1024 * 256);
  cvt_kernel<<<256, 256, 0, stream>>>(decWih, dWihB, 1024 * 256);
  cvt_kernel<<<1024, 256, 0, stream>>>(encWhh, eWhhB, 1024 * 1024);
  cvt_kernel<<<1024, 256, 0, stream>>>(decWhh, dWhhB, 1024 * 1024);
  cvt_kernel<<<512, 256, 0, stream>>>(outW, outWB, 512 * 1024);

  // projected-vocab tables: proj[v] = emb[v] @ Wih^T + bih + bhh  (512x1024)
  gemm_bt_kernel<<<128, 256, 0, stream>>>(embB, 0, eWihB, encBih, encBhh,
                                          projE, nullptr, 256, 1024, 16);
  gemm_bt_kernel<<<128, 256, 0, stream>>>(embB, 0, dWihB, decBih, decBhh,
                                          projD, nullptr, 256, 1024, 16);

  rnn_scan8_kernel<<<128, 256, 0, stream>>>(eWhhB, dWhhB, projE, projD,
                                            decBih, decBhh, inputs, outputs,
                                            hbuf, states, flags);

  out_gemm_lsm_kernel<<<512, 256, 0, stream>>>(states, outWB, outB, logits);
}